// Round 1
// baseline (25.146 us; speedup 1.0000x reference)
//
#include <hip/hip_runtime.h>

#define FD 32        // feature dim
#define TILE 64      // output tile edge per block
#define LSTRIDE (TILE + 4)   // padded LDS row stride (68 floats = 272B, 16B-aligned)

__global__ __launch_bounds__(256) void cheb_kernel(
    const float* __restrict__ A, const float* __restrict__ B,
    float* __restrict__ C, int N, int M)
{
    // Transposed tiles: s[d][row] so the d-loop reads contiguous float4 per thread.
    __shared__ float sA[FD][LSTRIDE];
    __shared__ float sB[FD][LSTRIDE];

    const int tid = threadIdx.x;
    const int r0 = blockIdx.y * TILE;   // rows of A / output rows
    const int c0 = blockIdx.x * TILE;   // rows of B / output cols

    // ---- Stage: 64 rows x 32 floats each for A and B = 512 float4 per matrix.
    // 256 threads -> 2 float4 each per matrix. Fully coalesced global reads.
#pragma unroll
    for (int k = 0; k < 2; ++k) {
        const int idx = tid + k * 256;      // 0..511
        const int row = idx >> 3;           // 0..63
        const int dq  = (idx & 7) * 4;      // d-quad start: 0,4,...,28
        const float4 va = *reinterpret_cast<const float4*>(A + (size_t)(r0 + row) * FD + dq);
        sA[dq + 0][row] = va.x;
        sA[dq + 1][row] = va.y;
        sA[dq + 2][row] = va.z;
        sA[dq + 3][row] = va.w;
        const float4 vb = *reinterpret_cast<const float4*>(B + (size_t)(c0 + row) * FD + dq);
        sB[dq + 0][row] = vb.x;
        sB[dq + 1][row] = vb.y;
        sB[dq + 2][row] = vb.z;
        sB[dq + 3][row] = vb.w;
    }
    __syncthreads();

    // ---- Compute: thread (tx,ty) owns 4x4 outputs at rows ty*4.., cols tx*4..
    const int tx = tid & 15;
    const int ty = tid >> 4;

    float acc[4][4];
#pragma unroll
    for (int i = 0; i < 4; ++i)
#pragma unroll
        for (int j = 0; j < 4; ++j)
            acc[i][j] = 0.0f;   // distances are >= 0

#pragma unroll
    for (int d = 0; d < FD; ++d) {
        const float4 a4 = *reinterpret_cast<const float4*>(&sA[d][ty * 4]);
        const float4 b4 = *reinterpret_cast<const float4*>(&sB[d][tx * 4]);
        const float a[4] = {a4.x, a4.y, a4.z, a4.w};
        const float b[4] = {b4.x, b4.y, b4.z, b4.w};
#pragma unroll
        for (int i = 0; i < 4; ++i)
#pragma unroll
            for (int j = 0; j < 4; ++j)
                acc[i][j] = fmaxf(acc[i][j], fabsf(a[i] - b[j]));
    }

    // ---- Write: 4 rows of float4, coalesced across tx.
#pragma unroll
    for (int i = 0; i < 4; ++i) {
        const int row = r0 + ty * 4 + i;
        float4 o;
        o.x = acc[i][0]; o.y = acc[i][1]; o.z = acc[i][2]; o.w = acc[i][3];
        *reinterpret_cast<float4*>(C + (size_t)row * M + c0 + tx * 4) = o;
    }
}

extern "C" void kernel_launch(void* const* d_in, const int* in_sizes, int n_in,
                              void* d_out, int out_size, void* d_ws, size_t ws_size,
                              hipStream_t stream) {
    const float* A = (const float*)d_in[0];
    const float* B = (const float*)d_in[1];
    float* C = (float*)d_out;
    const int N = in_sizes[0] / FD;   // 4096
    const int M = in_sizes[1] / FD;   // 4096
    dim3 grid(M / TILE, N / TILE);    // 64 x 64 tiles (N,M are multiples of 64 here)
    cheb_kernel<<<grid, 256, 0, stream>>>(A, B, C, N, M);
}